// Round 4
// baseline (559.619 us; speedup 1.0000x reference)
//
#include <hip/hip_runtime.h>
#include <hip/hip_bf16.h>
#include <cstdint>
#include <cstddef>

// ---------------------------------------------------------------------------
// ThermodynamicStateEngine fused kernel, round 4 (= round 3 resubmitted:
// round 3 never ran — GPU acquisition timeout).
// Round-1/2 failed identically (absmax 1.996 = decorrelated-noise signature).
// Root cause (theory): JAX >= 0.4.30 defaults jax_threefry_partitionable=True.
// random_bits is then PER-ELEMENT: ctr = (hi(i), lo(i)) = (0, i) and the two
// threefry2x32 output words are XOR-combined for 32-bit draws. (The legacy
// half-split scheme of rounds 1-2 is gone.) fold_in / key(42) use
// threefry_2x32 directly and are unaffected.
// Inputs identified by unique element count, not dict position.
// ---------------------------------------------------------------------------

#define N_TOK   16384
#define DIN     2048
#define DST     512
#define BM      128
#define BN      128
#define BK      32
#define LDK     40            // padded LDS row: 40 halves = 80 B

typedef __attribute__((ext_vector_type(4))) float  f32x4;
typedef __attribute__((ext_vector_type(8))) short  s16x8;
typedef __attribute__((ext_vector_type(8))) unsigned short u16x8;

// ---------------- compile-time threefry2x32 (JAX fold_in keys) -------------
constexpr unsigned long long tf_const(unsigned k0, unsigned k1,
                                      unsigned x0, unsigned x1) {
  unsigned ks[3] = {k0, k1, k0 ^ k1 ^ 0x1BD11BDAu};
  unsigned rot[8] = {13, 15, 26, 6, 17, 29, 16, 24};
  x0 += ks[0]; x1 += ks[1];
  for (int g = 0; g < 5; ++g) {
    for (int i = 0; i < 4; ++i) {
      unsigned r = rot[(g & 1) * 4 + i];
      x0 += x1;
      x1 = (x1 << r) | (x1 >> (32 - r));
      x1 ^= x0;
    }
    x0 += ks[(g + 1) % 3];
    x1 += ks[(g + 2) % 3] + (unsigned)(g + 1);
  }
  return ((unsigned long long)x1 << 32) | x0;
}

// key_s = threefry2x32(key=(0,42), ctr=(0,s)) == jax.random.fold_in(key(42), s)
// (fold_in goes through threefry_2x32 directly; NOT affected by the
//  partitionable flag.)
constexpr unsigned long long FK[5] = {
  tf_const(0u, 42u, 0u, 0u), tf_const(0u, 42u, 0u, 1u),
  tf_const(0u, 42u, 0u, 2u), tf_const(0u, 42u, 0u, 3u),
  tf_const(0u, 42u, 0u, 4u)
};

// ---------------- device threefry2x32 (20 rounds) ---------------------------
__device__ __forceinline__ void tf_dev(unsigned k0, unsigned k1,
                                       unsigned &x0, unsigned &x1) {
  unsigned ks2 = k0 ^ k1 ^ 0x1BD11BDAu;
  x0 += k0; x1 += k1;
#define TFR(r) { x0 += x1; x1 = (x1 << (r)) | (x1 >> (32 - (r))); x1 ^= x0; }
  TFR(13) TFR(15) TFR(26) TFR(6)   x0 += k1;  x1 += ks2 + 1u;
  TFR(17) TFR(29) TFR(16) TFR(24)  x0 += ks2; x1 += k0 + 2u;
  TFR(13) TFR(15) TFR(26) TFR(6)   x0 += k0;  x1 += k1 + 3u;
  TFR(17) TFR(29) TFR(16) TFR(24)  x0 += k1;  x1 += ks2 + 4u;
  TFR(13) TFR(15) TFR(26) TFR(6)   x0 += ks2; x1 += k0 + 5u;
#undef TFR
}

// partitionable threefry 32-bit draw at flat index idx (< 2^32 here):
// ctr64 = idx -> (hi, lo) = (0, idx); bits = out0 ^ out1.
__device__ __forceinline__ unsigned tf_bits32(unsigned k0, unsigned k1,
                                              unsigned idx) {
  unsigned a = 0u, b = idx;
  tf_dev(k0, k1, a, b);
  return a ^ b;
}

// bits -> N(0,1), bit-matching JAX: mantissa-uniform in [0,1), u = f*2+lo
// (f*2 exact; fp-contract to fma is harmless since the mul is exact),
// clamp, then sqrt(2)*erfinv with XLA's Giles f32 polynomial.
__device__ __forceinline__ float jax_normal(unsigned bits) {
  const float lo = -0x1.fffffep-1f;                 // nextafter(-1,0)
  float f = __uint_as_float((bits >> 9) | 0x3f800000u) - 1.0f;  // [0,1)
  float u = f * 2.0f + lo;
  u = fmaxf(lo, u);
  float w = -log1pf(-u * u);
  float p;
  if (w < 5.0f) {
    w -= 2.5f;
    p =               2.81022636e-08f;
    p = fmaf(p, w,    3.43273939e-07f);
    p = fmaf(p, w,   -3.5233877e-06f);
    p = fmaf(p, w,   -4.39150654e-06f);
    p = fmaf(p, w,    0.00021858087f);
    p = fmaf(p, w,   -0.00125372503f);
    p = fmaf(p, w,   -0.00417768164f);
    p = fmaf(p, w,    0.246640727f);
    p = fmaf(p, w,    1.50140941f);
  } else {
    w = sqrtf(w) - 3.0f;
    p =              -0.000200214257f;
    p = fmaf(p, w,    0.000100950558f);
    p = fmaf(p, w,    0.00134934322f);
    p = fmaf(p, w,   -0.00367342844f);
    p = fmaf(p, w,    0.00573950773f);
    p = fmaf(p, w,   -0.0076224613f);
    p = fmaf(p, w,    0.00943887047f);
    p = fmaf(p, w,    1.00167406f);
    p = fmaf(p, w,    2.83297682f);
  }
  return 1.41421356f * (p * u);
}

__device__ __forceinline__ float fast_tanh(float x) {
  float ax = fabsf(x);
  float e  = __expf(2.0f * ax);
  float t  = 1.0f - 2.0f * __builtin_amdgcn_rcpf(e + 1.0f);
  return copysignf(t, x);
}

__device__ __forceinline__ unsigned short f2bf(float x) {
  __hip_bfloat16 b = __float2bfloat16(x);   // RNE
  unsigned short u; __builtin_memcpy(&u, &b, 2);
  return u;
}

// ---------------- the fused kernel ------------------------------------------
__global__ __launch_bounds__(256, 2)
void k_fused(const float* __restrict__ h_init, const float* __restrict__ X,
             const float* __restrict__ sur, const float* __restrict__ W,
             float* __restrict__ out) {
  __shared__ union {
    float red[8];
    struct { unsigned short Ah[BM][LDK], Al[BM][LDK], Bh[BN][LDK], Bl[BN][LDK]; } t;
    float sc[32][256];
  } smem;
  __shared__ float s_scale;   // outside the union: must survive to epilogue

  const int tid  = threadIdx.x;
  const int bid  = blockIdx.x;
  const int bcol = bid & 3, brow = bid >> 2;
  const int r0 = brow * BM, c0 = bcol * BN;
  const int wave = tid >> 6, lane = tid & 63;
  const int wr = wave >> 1, wc = wave & 1;     // 2x2 waves, 64x64 each
  const int lrow = lane & 15, lkg = lane >> 4;

  // ---- phase 0: noise_scale, computed redundantly per block (no ws) ----
  {
    float s = 0.f;
    const f32x4* s4 = (const f32x4*)sur;
    for (int i = tid; i < N_TOK / 4; i += 256) {
      f32x4 v = s4[i];
      s += 1.f / (1.f + __expf(-v.x)) + 1.f / (1.f + __expf(-v.y)) +
           1.f / (1.f + __expf(-v.z)) + 1.f / (1.f + __expf(-v.w));
    }
#pragma unroll
    for (int o = 32; o > 0; o >>= 1) s += __shfl_down(s, o);
    if (lane == 0) smem.red[wave] = s;
    __syncthreads();
    if (tid == 0) {
      float tot = smem.red[0] + smem.red[1] + smem.red[2] + smem.red[3];
      s_scale = sqrtf(0.2f * (1.f + (tot / 16384.f) * 5.f));
    }
    __syncthreads();
  }

  f32x4 acc[4][4] = {};
  const int bc  = tid & 127;          // B-staging: my column
  const int bkh = (tid >> 7) * 16;    // B-staging: my k-half (0 or 16)

  for (int kt = 0; kt < DIN / BK; ++kt) {
    const int kbase = kt * BK;

    // ---- stage A tile: X fp32 -> bf16 hi/lo ----
#pragma unroll
    for (int i = 0; i < 2; ++i) {
      int c = tid + 256 * i;                  // 512 chunks of 8 floats
      int row = c >> 2, ks = c & 3;
      const float* src = X + (size_t)(r0 + row) * DIN + kbase + ks * 8;
      f32x4 v0 = *(const f32x4*)(src);
      f32x4 v1 = *(const f32x4*)(src + 4);
      float fv[8] = {v0.x, v0.y, v0.z, v0.w, v1.x, v1.y, v1.z, v1.w};
      u16x8 hi, lo2;
#pragma unroll
      for (int q = 0; q < 8; ++q) {
        unsigned short hq = f2bf(fv[q]);
        float hf = __uint_as_float((unsigned)hq << 16);
        hi[q]  = hq;
        lo2[q] = f2bf(fv[q] - hf);
      }
      *(u16x8*)&smem.t.Ah[row][ks * 8] = hi;
      *(u16x8*)&smem.t.Al[row][ks * 8] = lo2;
    }

    // ---- stage B tile straight from fp32 W [k][n], transpose to [n][k] ----
    {
      const float* wsrc = W + (size_t)(kbase + bkh) * DST + c0 + bc;
      u16x8 h0, h1, l0, l1;
#pragma unroll
      for (int i = 0; i < 16; ++i) {
        float v = wsrc[(size_t)i * DST];      // lanes read contiguous cols
        unsigned short hq = f2bf(v);
        float hf = __uint_as_float((unsigned)hq << 16);
        unsigned short lq = f2bf(v - hf);
        if (i < 8) { h0[i] = hq; l0[i] = lq; }
        else       { h1[i - 8] = hq; l1[i - 8] = lq; }
      }
      *(u16x8*)&smem.t.Bh[bc][bkh]     = h0;
      *(u16x8*)&smem.t.Bh[bc][bkh + 8] = h1;
      *(u16x8*)&smem.t.Bl[bc][bkh]     = l0;
      *(u16x8*)&smem.t.Bl[bc][bkh + 8] = l1;
    }
    __syncthreads();

    // ---- fragments + MFMA (3-term bf16 split) ----
    s16x8 afh[4], afl[4];
#pragma unroll
    for (int m = 0; m < 4; ++m) {
      int r = wr * 64 + m * 16 + lrow;
      afh[m] = *(const s16x8*)&smem.t.Ah[r][lkg * 8];
      afl[m] = *(const s16x8*)&smem.t.Al[r][lkg * 8];
    }
#pragma unroll
    for (int n = 0; n < 4; ++n) {
      int cc = wc * 64 + n * 16 + lrow;
      s16x8 bh = *(const s16x8*)&smem.t.Bh[cc][lkg * 8];
      s16x8 bl = *(const s16x8*)&smem.t.Bl[cc][lkg * 8];
#pragma unroll
      for (int m = 0; m < 4; ++m) {
        acc[m][n] = __builtin_amdgcn_mfma_f32_16x16x32_bf16(afh[m], bh, acc[m][n], 0, 0, 0);
        acc[m][n] = __builtin_amdgcn_mfma_f32_16x16x32_bf16(afl[m], bh, acc[m][n], 0, 0, 0);
        acc[m][n] = __builtin_amdgcn_mfma_f32_16x16x32_bf16(afh[m], bl, acc[m][n], 0, 0, 0);
      }
    }
    __syncthreads();
  }

  // ---- fused epilogue: tanh + 5-step Langevin, partitionable-threefry noise
  const float nscale = s_scale;

#pragma unroll
  for (int mp = 0; mp < 2; ++mp) {
    __syncthreads();
#pragma unroll
    for (int mm = 0; mm < 2; ++mm)
#pragma unroll
      for (int n = 0; n < 4; ++n)
#pragma unroll
        for (int j = 0; j < 4; ++j)
          smem.sc[mm * 16 + n * 4 + j][tid] = acc[mp * 2 + mm][n][j];
    __syncthreads();
    for (int e = 0; e < 32; ++e) {           // dynamic loop: small I-footprint
      float pre = smem.sc[e][tid];
      int mm = e >> 4, nn = (e >> 2) & 3, jj = e & 3;
      int row = r0 + wr * 64 + (mp * 2 + mm) * 16 + lkg * 4 + jj;
      int col = c0 + wc * 64 + nn * 16 + lrow;
      size_t off = (size_t)row * DST + col;
      float p = fast_tanh(pre);              // predicted_h
      float h = h_init[off];
      unsigned idx = (unsigned)off;
#pragma unroll
      for (int s = 0; s < 5; ++s) {
        unsigned bits = tf_bits32((unsigned)(FK[s] & 0xffffffffull),
                                  (unsigned)(FK[s] >> 32), idx);
        float nz = jax_normal(bits);
        float g = h - p;
        h = fast_tanh(h - g * 0.1f + nz * nscale);
      }
      out[off] = h;
    }
  }
}

// ---------------- host launcher --------------------------------------------
extern "C" void kernel_launch(void* const* d_in, const int* in_sizes, int n_in,
                              void* d_out, int out_size, void* d_ws, size_t ws_size,
                              hipStream_t stream) {
  // Identify inputs by their (unique) element counts — immune to ordering.
  const float *h_init = nullptr, *x = nullptr, *sur = nullptr, *W = nullptr;
  for (int i = 0; i < n_in; ++i) {
    switch (in_sizes[i]) {
      case N_TOK * DST:  h_init = (const float*)d_in[i]; break;  // 8388608
      case N_TOK * DIN:  x      = (const float*)d_in[i]; break;  // 33554432
      case N_TOK:        sur    = (const float*)d_in[i]; break;  // 16384
      case DIN * DST:    W      = (const float*)d_in[i]; break;  // 1048576
      default: break;
    }
  }
  float* out = (float*)d_out;
  (void)d_ws; (void)ws_size;

  k_fused<<<dim3(512), dim3(256), 0, stream>>>(h_init, x, sur, W, out);
}